// Round 4
// baseline (703.388 us; speedup 1.0000x reference)
//
#include <hip/hip_runtime.h>

#define H 64
#define NE 1500000
#define NLOC 20000
#define NEXP 200000
#define NL 400000
#define PAD_E 32
#define PAD_L 128

// ---- bucket-sort fill geometry ----
#define EB 896                        // experts per bucket (row LDS = 56KB)
#define NBE 224                       // ceil(200000/896)
#define LB 112                        // locs per bucket (row LDS = 56KB)
#define NBL 179                       // ceil(20000/112)
#define BIN_CHUNK 2048
#define NBIN ((NE + BIN_CHUNK - 1) / BIN_CHUNK)   // 733
#define EBSLOT 28                     // LDS slots per exp bucket per block
#define LBSLOT 32                     // LDS slots per loc bucket per block
#define ECAP 8192                     // exp queue capacity (lam 6696, +18 sigma)
#define LCAP 10240                    // loc queue capacity (lam 8380, +20 sigma)
#define FCAP 4096                     // fallback queue

// ---- workspace layout (bytes) ----
// cnt_loc [0,80000)  cnt_exp [80000,880000)
// nbr_loc [880064,11120064)  nbr_exp(u16) [11120064,23920064)
// Ylh(f16)  [23920064,26480064)   Y2fh(f16) [26480064,29040064)
// z_loc(f32)[29040064,34160064)   PH(f16)   [34160064,36720064)
// ZE(f16)   [39280064,64880064)   z_exph -> Qh (in-place)
// TH(f16)   [64880064,90480064)   T1h -> T2'h
//   (aliased pre-mfma: expQ [64880064,72220096) locQ [72220096,79551936)
//    qcnt [79551936,+1612) flbk_cnt [79553552) flbkQ [79554048,+32768))
// Wf_q [90480064) Wf_y2 [90496448) Wf_t2 [90512832) Wf_p [90529216)
// bf_q [90545600) bf_p [90545856)
#define WS_NEED 90546112ULL

typedef int vint4 __attribute__((ext_vector_type(4)));
typedef _Float16 f16x8 __attribute__((ext_vector_type(8)));
typedef float f32x4 __attribute__((ext_vector_type(4)));
typedef unsigned int u32;
typedef unsigned short u16;
typedef unsigned long long u64;

__device__ __forceinline__ float bcastf(float v, int k) {
  return __int_as_float(__builtin_amdgcn_readlane(__float_as_int(v), k));
}
__device__ __forceinline__ int bcasti(int v, int k) {
  return __builtin_amdgcn_readlane(v, k);
}

// ---------------- bucket-sort fill, pass 1: bin edges ----------------
__global__ __launch_bounds__(256) void bin_kernel(
    const int* __restrict__ src, const int* __restrict__ dst,
    u32* __restrict__ expQ, u32* __restrict__ locQ,
    int* __restrict__ qcnt, int* __restrict__ flbk_cnt,
    u64* __restrict__ flbkQ)
{
  __shared__ u32 eb[NBE * EBSLOT];   // 25088 B
  __shared__ u32 lb[NBL * LBSLOT];   // 22912 B
  __shared__ int ec[NBE], lc[NBL], ebase[NBE], lbase[NBL];  // 3224 B

  const int tid = threadIdx.x;
  for (int i = tid; i < NBE; i += 256) ec[i] = 0;
  for (int i = tid; i < NBL; i += 256) lc[i] = 0;
  __syncthreads();

  const long base = (long)blockIdx.x * BIN_CHUNK + tid * 8;
  if (base < NE) {   // NE % 8 == 0, so full 8-edge packet
    vint4 s0 = __builtin_nontemporal_load((const vint4*)(src + base));
    vint4 s1 = __builtin_nontemporal_load((const vint4*)(src + base + 4));
    vint4 d0 = __builtin_nontemporal_load((const vint4*)(dst + base));
    vint4 d1 = __builtin_nontemporal_load((const vint4*)(dst + base + 4));
    int ss[8] = {s0.x, s0.y, s0.z, s0.w, s1.x, s1.y, s1.z, s1.w};
    int dd[8] = {d0.x, d0.y, d0.z, d0.w, d1.x, d1.y, d1.z, d1.w};
#pragma unroll
    for (int k = 0; k < 8; k++) {
      const u32 d = (u32)dd[k], s = (u32)ss[k];
      {  // exp side: bucket by dst
        const u32 b = d / (u32)EB;
        const int pos = atomicAdd(&ec[b], 1);
        if (pos < EBSLOT) {
          eb[b * EBSLOT + pos] = ((d - b * EB) << 16) | s;
        } else {
          int fi = atomicAdd(flbk_cnt, 1);
          if (fi < FCAP) flbkQ[fi] = ((u64)d << 32) | (u64)s;   // side bit 0
        }
      }
      {  // loc side: bucket by src
        const u32 b = s / (u32)LB;
        const int pos = atomicAdd(&lc[b], 1);
        if (pos < LBSLOT) {
          lb[b * LBSLOT + pos] = ((s - b * LB) << 18) | d;
        } else {
          int fi = atomicAdd(flbk_cnt, 1);
          if (fi < FCAP) flbkQ[fi] = (1ULL << 63) | ((u64)s << 32) | (u64)d;
        }
      }
    }
  }
  __syncthreads();

  // reserve queue space (one global atomic per non-empty bucket, all parallel)
  for (int i = tid; i < NBE; i += 256) {
    const int c = min(ec[i], EBSLOT);
    ebase[i] = c ? atomicAdd(&qcnt[i], c) : 0;
  }
  for (int i = tid; i < NBL; i += 256) {
    const int c = min(lc[i], LBSLOT);
    lbase[i] = c ? atomicAdd(&qcnt[NBE + i], c) : 0;
  }
  __syncthreads();

  // flush dense runs (wave per bucket stripe)
  const int wid = tid >> 6, ln = tid & 63;
  for (int b = wid; b < NBE; b += 4) {
    const int c = min(ec[b], EBSLOT);
    if (ln < c) {
      const int idx = ebase[b] + ln;
      const u32 r = eb[b * EBSLOT + ln];
      if (idx < ECAP) {
        expQ[(long)b * ECAP + idx] = r;
      } else {
        int fi = atomicAdd(flbk_cnt, 1);
        if (fi < FCAP)
          flbkQ[fi] = ((u64)(b * EB + (r >> 16)) << 32) | (u64)(r & 0xFFFF);
      }
    }
  }
  for (int b = wid; b < NBL; b += 4) {
    const int c = min(lc[b], LBSLOT);
    if (ln < c) {
      const int idx = lbase[b] + ln;
      const u32 r = lb[b * LBSLOT + ln];
      if (idx < LCAP) {
        locQ[(long)b * LCAP + idx] = r;
      } else {
        int fi = atomicAdd(flbk_cnt, 1);
        if (fi < FCAP)
          flbkQ[fi] = (1ULL << 63) | ((u64)(b * LB + (r >> 18)) << 32) |
                      (u64)(r & 0x3FFFF);
      }
    }
  }
}

// ---------------- bucket-sort fill, pass 2: build padded CSR ----------------
__global__ __launch_bounds__(256) void build_kernel(
    const u32* __restrict__ expQ, const u32* __restrict__ locQ,
    const int* __restrict__ qcnt,
    u16* __restrict__ nbr_exp, int* __restrict__ nbr_loc,
    int* __restrict__ cnt_exp, int* __restrict__ cnt_loc)
{
  __shared__ char ldsraw[60928];
  const int tid = threadIdx.x;
  if (blockIdx.x < NBE) {
    const int b = blockIdx.x;
    u16* rows = (u16*)ldsraw;                 // EB*PAD_E u16 = 57344 B
    int* cnts = (int*)(ldsraw + 57344);       // EB ints  = 3584 B
    for (int i = tid; i < EB; i += 256) cnts[i] = 0;
    __syncthreads();
    const int n = min(qcnt[b], ECAP);
    for (int i = tid; i < n; i += 256) {
      const u32 r = expQ[(long)b * ECAP + i];
      const int nl = (int)(r >> 16);
      const int pos = atomicAdd(&cnts[nl], 1);
      if (pos < PAD_E) rows[nl * PAD_E + pos] = (u16)(r & 0xFFFF);
    }
    __syncthreads();
    const int node0 = b * EB;
    const int nn = min(EB, NEXP - node0);
    u32* grows = (u32*)(nbr_exp + (long)node0 * PAD_E);
    const u32* lrows = (const u32*)rows;
    for (int j = tid; j < nn * (PAD_E / 2); j += 256) grows[j] = lrows[j];
    for (int i = tid; i < nn; i += 256) cnt_exp[node0 + i] = cnts[i];
  } else {
    const int b = blockIdx.x - NBE;
    int* rows = (int*)ldsraw;                 // LB*PAD_L int = 57344 B
    int* cnts = (int*)(ldsraw + 57344);       // LB ints = 448 B
    for (int i = tid; i < LB; i += 256) cnts[i] = 0;
    __syncthreads();
    const int n = min(qcnt[NBE + b], LCAP);
    for (int i = tid; i < n; i += 256) {
      const u32 r = locQ[(long)b * LCAP + i];
      const int sl = (int)(r >> 18);
      const int pos = atomicAdd(&cnts[sl], 1);
      if (pos < PAD_L) rows[sl * PAD_L + pos] = (int)(r & 0x3FFFF);
    }
    __syncthreads();
    const int node0 = b * LB;
    const int nn = min(LB, NLOC - node0);
    int* grows = nbr_loc + (long)node0 * PAD_L;
    for (int j = tid; j < nn * PAD_L; j += 256) grows[j] = rows[j];
    for (int i = tid; i < nn; i += 256) cnt_loc[node0 + i] = cnts[i];
  }
}

// prep_kernel: fold (blk 0-4) + fallback drain (blk 5) + dense Ylh (blk >=6).
// Merges the old fold_kernel and dense#1 launch: fold's 6-block grid no
// longer serializes the pipeline; one fewer dispatch.
__global__ __launch_bounds__(256) void prep_kernel(
    const float* __restrict__ W2r_of, const float* __restrict__ W2l_of,
    const float* __restrict__ W2l_rev, const float* __restrict__ W2r_rev,
    const float* __restrict__ dW1, const float* __restrict__ b2_of,
    const float* __restrict__ b2_rev,
    float* __restrict__ Wf_q, float* __restrict__ Wf_y2,
    float* __restrict__ Wf_t2, float* __restrict__ Wf_p,
    float* __restrict__ bf_q, float* __restrict__ bf_p,
    const int* __restrict__ flbk_cnt, const u64* __restrict__ flbkQ,
    u16* __restrict__ nbr_exp, int* __restrict__ nbr_loc,
    int* __restrict__ cnt_exp, int* __restrict__ cnt_loc,
    const float* __restrict__ emb_loc, _Float16* __restrict__ Ylh,
    const float* __restrict__ W1l_of)
{
  const int lane = threadIdx.x & 63;
  const int w = threadIdx.x >> 6;
  const float* dW1a = dW1;
  const float* dW1b = dW1 + H * H;
  if (blockIdx.x < 4) {
    const float* A; const float* B; float* C;
    switch (blockIdx.x) {
      case 0:  A = W2r_of;  B = dW1b; C = Wf_q;  break;
      case 1:  A = W2l_of;  B = dW1b; C = Wf_y2; break;
      case 2:  A = W2l_rev; B = dW1a; C = Wf_t2; break;
      default: A = W2r_rev; B = dW1a; C = Wf_p;  break;
    }
    float b[H];
#pragma unroll
    for (int k = 0; k < H; k++) b[k] = B[k * H + lane];
    for (int r = w * 16; r < w * 16 + 16; r++) {
      const float xv = A[r * H + lane];
      float a0 = 0.f, a1 = 0.f;
#pragma unroll
      for (int k = 0; k < H; k += 2) {
        a0 += bcastf(xv, k)     * b[k];
        a1 += bcastf(xv, k + 1) * b[k + 1];
      }
      C[r * H + lane] = a0 + a1;
    }
  } else if (blockIdx.x == 4) {
    if (w < 2) {
      const float* bv_src = (w == 0) ? b2_of : b2_rev;
      const float* B      = (w == 0) ? dW1b  : dW1a;
      float* o            = (w == 0) ? bf_q  : bf_p;
      float wk[H];
#pragma unroll
      for (int k = 0; k < H; k++) wk[k] = B[k * H + lane];
      const float bv = bv_src[lane];
      float a = 0.f;
#pragma unroll
      for (int k = 0; k < H; k++) a += bcastf(bv, k) * wk[k];
      o[lane] = a;
    }
  } else if (blockIdx.x == 5) {
    // drain fallback queue (rare Poisson-tail edges; keeps fill exact)
    const int n = min(*flbk_cnt, FCAP);
    for (int i = threadIdx.x; i < n; i += 256) {
      const u64 rec = flbkQ[i];
      const int node = (int)((rec >> 32) & 0x3FFFF);
      const int val  = (int)(rec & 0x3FFFF);
      if ((rec >> 63) == 0) {
        int pos = atomicAdd(&cnt_exp[node], 1);
        if (pos < PAD_E) nbr_exp[(long)node * PAD_E + pos] = (u16)val;
      } else {
        int pos = atomicAdd(&cnt_loc[node], 1);
        if (pos < PAD_L) nbr_loc[(long)node * PAD_L + pos] = val;
      }
    }
  } else {
    // dense: Ylh = emb_loc @ W1l_of (fp16 out), 64 rows per block
    float wreg[H];
#pragma unroll
    for (int k = 0; k < H; k++) wreg[k] = W1l_of[k * H + lane];
    const int rbase = (blockIdx.x - 6) * 64 + w * 16;
    for (int rr = 0; rr < 16; rr++) {
      const int r = rbase + rr;
      if (r >= NLOC) break;
      const float xv = emb_loc[(long)r * H + lane];
      float a0 = 0.f, a1 = 0.f;
#pragma unroll
      for (int k = 0; k < H; k += 2) {
        a0 += bcastf(xv, k)     * wreg[k];
        a1 += bcastf(xv, k + 1) * wreg[k + 1];
      }
      Ylh[(long)r * H + lane] = (_Float16)(a0 + a1);
    }
  }
}

// out16 = x @ W (no bias); fp32 in, fp16 out.
__global__ __launch_bounds__(256, 4) void dense_linear_kernel(
    const float* __restrict__ x, _Float16* __restrict__ out16,
    const float* __restrict__ W, int n)
{
  const int lane = threadIdx.x & 63;
  const int gw = (blockIdx.x * 256 + threadIdx.x) >> 6;
  const int nw = (gridDim.x * 256) >> 6;
  float w[H];
#pragma unroll
  for (int k = 0; k < H; k++) w[k] = W[k * H + lane];
  for (int i = gw; i < n; i += nw) {
    const float xv = x[i * H + lane];
    float a0 = 0.f, a1 = 0.f;
#pragma unroll
    for (int k = 0; k < H; k += 2) {
      a0 += bcastf(xv, k)     * w[k];
      a1 += bcastf(xv, k + 1) * w[k + 1];
    }
    out16[i * H + lane] = (_Float16)(a0 + a1);
  }
}

// Exp-side MFMA pass (dual-B, optional gather/bias/relu). Block = 16 rows.
// r4: gather restructured for MLP — prefetch 4 cnts + 4 id-vectors, then
// interleave the 4 rows' k-loops (8 independent loads in flight vs 4
// serial); A-fragment loads hoisted above the gather; Gs stride 68 kills
// the 4-way LDS read conflict.
__global__ __launch_bounds__(256, 4) void mfma_pass_kernel(
    const u16* __restrict__ nbr, const int* __restrict__ cnt,
    const _Float16* __restrict__ y,
    const float* a32, const _Float16* a16,
    _Float16* out1, const float* __restrict__ W1,
    const float* __restrict__ bias, int relu,
    _Float16* out2, const float* __restrict__ W2)
{
  const int w = threadIdx.x >> 6;
  const int lane = threadIdx.x & 63;
  const int q = lane >> 4;
  const int cidx = lane & 15;
  const int rb = blockIdx.x * 16;

  __shared__ float Gs[16 * 68];

  f16x8 b1lo, b1hi, b2lo, b2hi;
#pragma unroll
  for (int j = 0; j < 8; j++) {
    b1lo[j] = (_Float16)W1[(q * 8 + j) * H + w * 16 + cidx];
    b1hi[j] = (_Float16)W1[(32 + q * 8 + j) * H + w * 16 + cidx];
  }
  if (out2) {
#pragma unroll
    for (int j = 0; j < 8; j++) {
      b2lo[j] = (_Float16)W2[(q * 8 + j) * H + w * 16 + cidx];
      b2hi[j] = (_Float16)W2[(32 + q * 8 + j) * H + w * 16 + cidx];
    }
  }

  // A-fragment load hoisted above the gather (independent; overlaps latency)
  f16x8 a0, a1;
  if (a16) {
    const _Float16* ar = a16 + (long)(rb + cidx) * H;
    a0 = *(const f16x8*)(ar + q * 8);
    a1 = *(const f16x8*)(ar + 32 + q * 8);
  } else {
    const float* ar = a32 + (long)(rb + cidx) * H;
    f32x4 v0 = *(const f32x4*)(ar + q * 8);
    f32x4 v1 = *(const f32x4*)(ar + q * 8 + 4);
    f32x4 v2 = *(const f32x4*)(ar + 32 + q * 8);
    f32x4 v3 = *(const f32x4*)(ar + 32 + q * 8 + 4);
#pragma unroll
    for (int j = 0; j < 4; j++) {
      a0[j] = (_Float16)v0[j];
      a0[j + 4] = (_Float16)v1[j];
      a1[j] = (_Float16)v2[j];
      a1[j + 4] = (_Float16)v3[j];
    }
  }

  if (y) {
    const int i0r = rb + w * 4;
    int c4[4];
#pragma unroll
    for (int rr = 0; rr < 4; rr++) c4[rr] = cnt[i0r + rr];
    int id4[4];
#pragma unroll
    for (int rr = 0; rr < 4; rr++) {
      const int c = min(c4[rr], PAD_E);
      id4[rr] = (lane < c) ? (int)nbr[(long)(i0r + rr) * PAD_E + lane] : 0;
    }
    float sa[4] = {0.f, 0.f, 0.f, 0.f}, sb[4] = {0.f, 0.f, 0.f, 0.f};
    const int cm = min(max(max(c4[0], c4[1]), max(c4[2], c4[3])), PAD_E);
    for (int k = 0; k < cm; k += 2) {
#pragma unroll
      for (int rr = 0; rr < 4; rr++) {
        const int c = min(c4[rr], PAD_E);
        if (k < c)
          sa[rr] += (float)y[(long)bcasti(id4[rr], k) * H + lane];
        if (k + 1 < c)
          sb[rr] += (float)y[(long)bcasti(id4[rr], k + 1) * H + lane];
      }
    }
#pragma unroll
    for (int rr = 0; rr < 4; rr++)
      Gs[(w * 4 + rr) * 68 + lane] =
          (sa[rr] + sb[rr]) / fmaxf((float)c4[rr], 1.0f);
  }

  f32x4 acc1 = {0.f, 0.f, 0.f, 0.f};
  acc1 = __builtin_amdgcn_mfma_f32_16x16x32_f16(a0, b1lo, acc1, 0, 0, 0);
  acc1 = __builtin_amdgcn_mfma_f32_16x16x32_f16(a1, b1hi, acc1, 0, 0, 0);
  f32x4 acc2 = {0.f, 0.f, 0.f, 0.f};
  if (out2) {
    acc2 = __builtin_amdgcn_mfma_f32_16x16x32_f16(a0, b2lo, acc2, 0, 0, 0);
    acc2 = __builtin_amdgcn_mfma_f32_16x16x32_f16(a1, b2hi, acc2, 0, 0, 0);
  }

  const float bj = bias ? bias[w * 16 + cidx] : 0.f;
  __syncthreads();   // Gs ready; all A loads drained before in-place stores
#pragma unroll
  for (int reg = 0; reg < 4; reg++) {
    const int r = q * 4 + reg;
    float v = acc1[reg] + bj;
    if (y) v += Gs[r * 68 + w * 16 + cidx];
    if (relu) v = fmaxf(v, 0.f);
    out1[(long)(rb + r) * H + w * 16 + cidx] = (_Float16)v;
    if (out2)
      out2[(long)(rb + r) * H + w * 16 + cidx] = (_Float16)acc2[reg];
  }
}

// Loc side: out = mean-gather(fp16 T rows) + x @ Wr + bias (opt relu).
// r4: 2 rows processed jointly with interleaved k-loop (doubles loads in
// flight; removes per-row serial latency chains).
__global__ __launch_bounds__(256, 4) void loc_gather_kernel(
    const int* __restrict__ nbr, const int* __restrict__ cnt,
    const _Float16* __restrict__ T, const float* __restrict__ x,
    float* __restrict__ out32, _Float16* __restrict__ out16,
    const float* __restrict__ Wr, const float* __restrict__ bias,
    int n, int relu)
{
  const int lane = threadIdx.x & 63;
  const int gw = (blockIdx.x * 256 + threadIdx.x) >> 6;
  const int nw = (gridDim.x * 256) >> 6;
  float wr[H];
#pragma unroll
  for (int k = 0; k < H; k++) wr[k] = Wr[k * H + lane];
  const float bj = bias[lane];
  for (int i = gw * 2; i < n; i += nw * 2) {   // n even; i+1 < n always
    const int c0 = cnt[i], c1 = cnt[i + 1];
    const int cc0 = min(c0, PAD_L), cc1 = min(c1, PAD_L);
    const int* nb0 = nbr + (long)i * PAD_L;
    const int* nb1 = nb0 + PAD_L;
    float s0a = 0.f, s0b = 0.f, s1a = 0.f, s1b = 0.f;
    for (int e = 0; e < PAD_L; e += 64) {
      const int m0 = min(cc0 - e, 64);
      const int m1 = min(cc1 - e, 64);
      if (m0 <= 0 && m1 <= 0) break;
      const int id0 = (lane < m0) ? nb0[e + lane] : 0;
      const int id1 = (lane < m1) ? nb1[e + lane] : 0;
      const int km = max(m0, m1);
      for (int k = 0; k < km; k += 2) {
        if (k < m0)
          s0a += (float)T[(long)bcasti(id0, k) * H + lane];
        if (k + 1 < m0)
          s0b += (float)T[(long)bcasti(id0, k + 1) * H + lane];
        if (k < m1)
          s1a += (float)T[(long)bcasti(id1, k) * H + lane];
        if (k + 1 < m1)
          s1b += (float)T[(long)bcasti(id1, k + 1) * H + lane];
      }
    }
    const float agg0 = (s0a + s0b) / fmaxf((float)c0, 1.0f);
    const float agg1 = (s1a + s1b) / fmaxf((float)c1, 1.0f);
    const float xv0 = x[(long)i * H + lane];
    const float xv1 = x[(long)(i + 1) * H + lane];
    float a00 = 0.f, a01 = 0.f, a10 = 0.f, a11 = 0.f;
#pragma unroll
    for (int k = 0; k < H; k += 2) {
      a00 += bcastf(xv0, k)     * wr[k];
      a01 += bcastf(xv0, k + 1) * wr[k + 1];
      a10 += bcastf(xv1, k)     * wr[k];
      a11 += bcastf(xv1, k + 1) * wr[k + 1];
    }
    float acc0 = agg0 + bj + a00 + a01;
    float acc1 = agg1 + bj + a10 + a11;
    if (relu) { acc0 = fmaxf(acc0, 0.0f); acc1 = fmaxf(acc1, 0.0f); }
    if (out32) {
      out32[(long)i * H + lane] = acc0;
      out32[(long)(i + 1) * H + lane] = acc1;
    } else {
      out16[(long)i * H + lane] = (_Float16)acc0;
      out16[(long)(i + 1) * H + lane] = (_Float16)acc1;
    }
  }
}

// out[e] = sum_j relu(P[r,j] + Q[c,j] + db1[j]) * dW2[j] + db2  (P,Q fp16)
__global__ __launch_bounds__(256, 4) void edge_kernel(
    const int* __restrict__ row, const int* __restrict__ col,
    const _Float16* __restrict__ P, const _Float16* __restrict__ Q,
    const float* __restrict__ db1, const float* __restrict__ dW2,
    const float* __restrict__ db2, float* __restrict__ out)
{
  const int lane = threadIdx.x & 63;
  const int gw = (blockIdx.x * 256 + threadIdx.x) >> 6;
  const int nw = (gridDim.x * 256) >> 6;
  const float bj = db1[lane];
  const float w2 = dW2[lane];
  const float b2 = db2[0];
  for (int e = gw * 4; e < NL; e += nw * 4) {
    const int n4 = min(NL - e, 4);
    float h[4];
#pragma unroll
    for (int k = 0; k < 4; k++) {
      if (k < n4) {
        const int r = row[e + k], c = col[e + k];
        const float p = (float)P[(long)r * H + lane];
        const float q = (float)Q[(long)c * H + lane];
        h[k] = fmaxf(p + q + bj, 0.0f) * w2;
      } else h[k] = 0.f;
    }
#pragma unroll
    for (int off = 1; off < 64; off <<= 1) {
#pragma unroll
      for (int k = 0; k < 4; k++) h[k] += __shfl_xor(h[k], off);
    }
    if (lane == 0) {
#pragma unroll
      for (int k = 0; k < 4; k++)
        if (k < n4) out[e + k] = h[k] + b2;
    }
  }
}

extern "C" void kernel_launch(void* const* d_in, const int* in_sizes, int n_in,
                              void* d_out, int out_size, void* d_ws, size_t ws_size,
                              hipStream_t stream) {
  const float* emb_loc = (const float*)d_in[0];
  const float* emb_exp = (const float*)d_in[1];
  const float* W1l_of  = (const float*)d_in[2];
  const float* b1_of   = (const float*)d_in[3];
  const float* W1r_of  = (const float*)d_in[4];
  const float* W1l_rev = (const float*)d_in[5];
  const float* b1_rev  = (const float*)d_in[6];
  const float* W1r_rev = (const float*)d_in[7];
  const float* W2l_of  = (const float*)d_in[8];
  const float* b2_of   = (const float*)d_in[9];
  const float* W2r_of  = (const float*)d_in[10];
  const float* W2l_rev = (const float*)d_in[11];
  const float* b2_rev  = (const float*)d_in[12];
  const float* W2r_rev = (const float*)d_in[13];
  const float* dW1     = (const float*)d_in[14];
  const float* db1     = (const float*)d_in[15];
  const float* dW2     = (const float*)d_in[16];
  const float* db2     = (const float*)d_in[17];
  const int*   edge_of = (const int*)d_in[18];
  const int*   eli     = (const int*)d_in[20];

  const int* src = edge_of;
  const int* dst = edge_of + NE;
  const int* row = eli;
  const int* col = eli + NL;

  if (ws_size < WS_NEED) return;

  char* ws = (char*)d_ws;
  int*            cnt_loc = (int*)(ws);
  int*            cnt_exp = (int*)(ws + 80000);
  int*            nbr_loc = (int*)(ws + 880064);
  unsigned short* nbr_exp = (unsigned short*)(ws + 11120064);
  _Float16*       Ylh     = (_Float16*)(ws + 23920064);
  _Float16*       Y2fh    = (_Float16*)(ws + 26480064);
  float*          z_loc   = (float*)(ws + 29040064);
  _Float16*       PH      = (_Float16*)(ws + 34160064);
  _Float16*       ZE      = (_Float16*)(ws + 39280064);
  _Float16*       TH      = (_Float16*)(ws + 64880064);
  // fill-time aliases over the TH region (dead until mfma pass #1)
  u32*            expQ    = (u32*)(ws + 64880064);
  u32*            locQ    = (u32*)(ws + 72220096);
  int*            qcnt    = (int*)(ws + 79551936);
  int*            flbk    = (int*)(ws + 79553552);
  u64*            flbkQ   = (u64*)(ws + 79554048);
  float*          Wf_q    = (float*)(ws + 90480064);
  float*          Wf_y2   = (float*)(ws + 90496448);
  float*          Wf_t2   = (float*)(ws + 90512832);
  float*          Wf_p    = (float*)(ws + 90529216);
  float*          bf_q    = (float*)(ws + 90545600);
  float*          bf_p    = (float*)(ws + 90545856);
  float*          out     = (float*)d_out;

  // zero queue counters + fallback counter only
  (void)hipMemsetAsync(ws + 79551936, 0, 2048, stream);

  // ---- CSR fill: bin -> build (full-line writes) ----
  bin_kernel<<<NBIN, 256, 0, stream>>>(src, dst, expQ, locQ, qcnt, flbk, flbkQ);
  build_kernel<<<NBE + NBL, 256, 0, stream>>>(expQ, locQ, qcnt,
      nbr_exp, nbr_loc, cnt_exp, cnt_loc);
  // fold + fallback drain + dense#1 in one launch
  prep_kernel<<<320, 256, 0, stream>>>(W2r_of, W2l_of, W2l_rev, W2r_rev,
                                       dW1, b2_of, b2_rev,
                                       Wf_q, Wf_y2, Wf_t2, Wf_p, bf_q, bf_p,
                                       flbk, flbkQ, nbr_exp, nbr_loc,
                                       cnt_exp, cnt_loc,
                                       emb_loc, Ylh, W1l_of);

  // ---- layer 1 ----
  // passA: z_exph = relu(emb_exp@W1r_of + gatherE(Ylh) + b1_of); T1h = emb_exp@W1l_rev
  mfma_pass_kernel<<<NEXP / 16, 256, 0, stream>>>(nbr_exp, cnt_exp, Ylh,
      emb_exp, (const _Float16*)nullptr, ZE, W1r_of, b1_of, 1, TH, W1l_rev);
  loc_gather_kernel<<<1250, 256, 0, stream>>>(nbr_loc, cnt_loc, TH,
      emb_loc, z_loc, (_Float16*)nullptr, W1r_rev, b1_rev, NLOC, 1);

  // ---- layer 2 + decoder transforms (folded: no relu on layer 2) ----
  dense_linear_kernel<<<1280, 256, 0, stream>>>(z_loc, Y2fh, Wf_y2, NLOC);
  // passB: Qh = z_exph@Wf_q + gatherE(Y2fh) + bf_q (in-place over ZE);
  //        T2'h = z_exph@Wf_t2 (over TH; T1h consumed)
  mfma_pass_kernel<<<NEXP / 16, 256, 0, stream>>>(nbr_exp, cnt_exp, Y2fh,
      (const float*)nullptr, ZE, ZE, Wf_q, bf_q, 0, TH, Wf_t2);
  // PH = gatherL(T2'h) + z_loc@Wf_p + bf_p   (decoder-left, folded, fp16 out)
  loc_gather_kernel<<<1250, 256, 0, stream>>>(nbr_loc, cnt_loc, TH,
      z_loc, (float*)nullptr, PH, Wf_p, bf_p, NLOC, 0);

  // ---- decoder edge pass ----
  edge_kernel<<<2048, 256, 0, stream>>>(row, col, PH, ZE,
                                        db1, dW2, db2, out);
}

// Round 5
// 513.107 us; speedup vs baseline: 1.3708x; 1.3708x over previous
//
#include <hip/hip_runtime.h>

#define H 64
#define NE 1500000
#define NLOC 20000
#define NEXP 200000
#define NL 400000
#define PAD_E 32
#define PAD_L 128

// ---- bucket-sort fill geometry ----
#define EB 896                        // experts per bucket (row LDS = 56KB)
#define NBE 224                       // ceil(200000/896)
#define LB 112                        // locs per bucket (row LDS = 56KB)
#define NBL 179                       // ceil(20000/112)
#define BIN_CHUNK 2048
#define NBIN ((NE + BIN_CHUNK - 1) / BIN_CHUNK)   // 733
#define EBSLOT 28                     // LDS slots per exp bucket per block
#define LBSLOT 32                     // LDS slots per loc bucket per block
#define ECAP 8192                     // exp queue capacity (lam 6696, +18 sigma)
#define LCAP 10240                    // loc queue capacity (lam 8380, +20 sigma)
#define FCAP 4096                     // fallback queue

// ---- workspace layout (bytes) ----
// cnt_loc [0,80000)  cnt_exp [80000,880000)
// nbr_loc [880064,11120064)  nbr_exp(u16) [11120064,23920064)
// Ylh(f16)  [23920064,26480064)   Y2fh(f16) [26480064,29040064)
// z_loc(f32)[29040064,34160064)   PH(f16)   [34160064,36720064)
// ZE(f16)   [39280064,64880064)   z_exph -> Qh (in-place)
// TH(f16)   [64880064,90480064)   T1h -> T2'h
//   (aliased pre-mfma: expQ [64880064,72220096) locQ [72220096,79551936)
//    qcnt [79551936,+1612) flbk_cnt [79553552) flbkQ [79554048,+32768))
// Wf_q [90480064) Wf_y2 [90496448) Wf_t2 [90512832) Wf_p [90529216)
// bf_q [90545600) bf_p [90545856)
#define WS_NEED 90546112ULL

typedef int vint4 __attribute__((ext_vector_type(4)));
typedef _Float16 f16x8 __attribute__((ext_vector_type(8)));
typedef float f32x4 __attribute__((ext_vector_type(4)));
typedef unsigned int u32;
typedef unsigned short u16;
typedef unsigned long long u64;

__device__ __forceinline__ float bcastf(float v, int k) {
  return __int_as_float(__builtin_amdgcn_readlane(__float_as_int(v), k));
}
__device__ __forceinline__ int bcasti(int v, int k) {
  return __builtin_amdgcn_readlane(v, k);
}

// ---------------- bucket-sort fill, pass 1: bin edges ----------------
__global__ __launch_bounds__(256) void bin_kernel(
    const int* __restrict__ src, const int* __restrict__ dst,
    u32* __restrict__ expQ, u32* __restrict__ locQ,
    int* __restrict__ qcnt, int* __restrict__ flbk_cnt,
    u64* __restrict__ flbkQ)
{
  __shared__ u32 eb[NBE * EBSLOT];   // 25088 B
  __shared__ u32 lb[NBL * LBSLOT];   // 22912 B
  __shared__ int ec[NBE], lc[NBL], ebase[NBE], lbase[NBL];  // 3224 B

  const int tid = threadIdx.x;
  for (int i = tid; i < NBE; i += 256) ec[i] = 0;
  for (int i = tid; i < NBL; i += 256) lc[i] = 0;
  __syncthreads();

  const long base = (long)blockIdx.x * BIN_CHUNK + tid * 8;
  if (base < NE) {   // NE % 8 == 0, so full 8-edge packet
    vint4 s0 = __builtin_nontemporal_load((const vint4*)(src + base));
    vint4 s1 = __builtin_nontemporal_load((const vint4*)(src + base + 4));
    vint4 d0 = __builtin_nontemporal_load((const vint4*)(dst + base));
    vint4 d1 = __builtin_nontemporal_load((const vint4*)(dst + base + 4));
    int ss[8] = {s0.x, s0.y, s0.z, s0.w, s1.x, s1.y, s1.z, s1.w};
    int dd[8] = {d0.x, d0.y, d0.z, d0.w, d1.x, d1.y, d1.z, d1.w};
#pragma unroll
    for (int k = 0; k < 8; k++) {
      const u32 d = (u32)dd[k], s = (u32)ss[k];
      {  // exp side: bucket by dst
        const u32 b = d / (u32)EB;
        const int pos = atomicAdd(&ec[b], 1);
        if (pos < EBSLOT) {
          eb[b * EBSLOT + pos] = ((d - b * EB) << 16) | s;
        } else {
          int fi = atomicAdd(flbk_cnt, 1);
          if (fi < FCAP) flbkQ[fi] = ((u64)d << 32) | (u64)s;   // side bit 0
        }
      }
      {  // loc side: bucket by src
        const u32 b = s / (u32)LB;
        const int pos = atomicAdd(&lc[b], 1);
        if (pos < LBSLOT) {
          lb[b * LBSLOT + pos] = ((s - b * LB) << 18) | d;
        } else {
          int fi = atomicAdd(flbk_cnt, 1);
          if (fi < FCAP) flbkQ[fi] = (1ULL << 63) | ((u64)s << 32) | (u64)d;
        }
      }
    }
  }
  __syncthreads();

  // reserve queue space (one global atomic per non-empty bucket, all parallel)
  for (int i = tid; i < NBE; i += 256) {
    const int c = min(ec[i], EBSLOT);
    ebase[i] = c ? atomicAdd(&qcnt[i], c) : 0;
  }
  for (int i = tid; i < NBL; i += 256) {
    const int c = min(lc[i], LBSLOT);
    lbase[i] = c ? atomicAdd(&qcnt[NBE + i], c) : 0;
  }
  __syncthreads();

  // flush dense runs (wave per bucket stripe)
  const int wid = tid >> 6, ln = tid & 63;
  for (int b = wid; b < NBE; b += 4) {
    const int c = min(ec[b], EBSLOT);
    if (ln < c) {
      const int idx = ebase[b] + ln;
      const u32 r = eb[b * EBSLOT + ln];
      if (idx < ECAP) {
        expQ[(long)b * ECAP + idx] = r;
      } else {
        int fi = atomicAdd(flbk_cnt, 1);
        if (fi < FCAP)
          flbkQ[fi] = ((u64)(b * EB + (r >> 16)) << 32) | (u64)(r & 0xFFFF);
      }
    }
  }
  for (int b = wid; b < NBL; b += 4) {
    const int c = min(lc[b], LBSLOT);
    if (ln < c) {
      const int idx = lbase[b] + ln;
      const u32 r = lb[b * LBSLOT + ln];
      if (idx < LCAP) {
        locQ[(long)b * LCAP + idx] = r;
      } else {
        int fi = atomicAdd(flbk_cnt, 1);
        if (fi < FCAP)
          flbkQ[fi] = (1ULL << 63) | ((u64)(b * LB + (r >> 18)) << 32) |
                      (u64)(r & 0x3FFFF);
      }
    }
  }
}

// ---------------- bucket-sort fill, pass 2: build padded CSR ----------------
__global__ __launch_bounds__(256) void build_kernel(
    const u32* __restrict__ expQ, const u32* __restrict__ locQ,
    const int* __restrict__ qcnt,
    u16* __restrict__ nbr_exp, int* __restrict__ nbr_loc,
    int* __restrict__ cnt_exp, int* __restrict__ cnt_loc)
{
  __shared__ char ldsraw[60928];
  const int tid = threadIdx.x;
  if (blockIdx.x < NBE) {
    const int b = blockIdx.x;
    u16* rows = (u16*)ldsraw;                 // EB*PAD_E u16 = 57344 B
    int* cnts = (int*)(ldsraw + 57344);       // EB ints  = 3584 B
    for (int i = tid; i < EB; i += 256) cnts[i] = 0;
    __syncthreads();
    const int n = min(qcnt[b], ECAP);
    for (int i = tid; i < n; i += 256) {
      const u32 r = expQ[(long)b * ECAP + i];
      const int nl = (int)(r >> 16);
      const int pos = atomicAdd(&cnts[nl], 1);
      if (pos < PAD_E) rows[nl * PAD_E + pos] = (u16)(r & 0xFFFF);
    }
    __syncthreads();
    const int node0 = b * EB;
    const int nn = min(EB, NEXP - node0);
    u32* grows = (u32*)(nbr_exp + (long)node0 * PAD_E);
    const u32* lrows = (const u32*)rows;
    for (int j = tid; j < nn * (PAD_E / 2); j += 256) grows[j] = lrows[j];
    for (int i = tid; i < nn; i += 256) cnt_exp[node0 + i] = cnts[i];
  } else {
    const int b = blockIdx.x - NBE;
    int* rows = (int*)ldsraw;                 // LB*PAD_L int = 57344 B
    int* cnts = (int*)(ldsraw + 57344);       // LB ints = 448 B
    for (int i = tid; i < LB; i += 256) cnts[i] = 0;
    __syncthreads();
    const int n = min(qcnt[NBE + b], LCAP);
    for (int i = tid; i < n; i += 256) {
      const u32 r = locQ[(long)b * LCAP + i];
      const int sl = (int)(r >> 18);
      const int pos = atomicAdd(&cnts[sl], 1);
      if (pos < PAD_L) rows[sl * PAD_L + pos] = (int)(r & 0x3FFFF);
    }
    __syncthreads();
    const int node0 = b * LB;
    const int nn = min(LB, NLOC - node0);
    int* grows = nbr_loc + (long)node0 * PAD_L;
    for (int j = tid; j < nn * PAD_L; j += 256) grows[j] = rows[j];
    for (int i = tid; i < nn; i += 256) cnt_loc[node0 + i] = cnts[i];
  }
}

// prep_kernel: fold (blk 0-4) + fallback drain (blk 5) + dense Ylh (blk >=6).
// r5: dense branch back to grid-stride (4 rows/wave, 5000 waves) — r4's
// 16-serial-rows/wave at 15% occupancy was latency-exposed.
__global__ __launch_bounds__(256) void prep_kernel(
    const float* __restrict__ W2r_of, const float* __restrict__ W2l_of,
    const float* __restrict__ W2l_rev, const float* __restrict__ W2r_rev,
    const float* __restrict__ dW1, const float* __restrict__ b2_of,
    const float* __restrict__ b2_rev,
    float* __restrict__ Wf_q, float* __restrict__ Wf_y2,
    float* __restrict__ Wf_t2, float* __restrict__ Wf_p,
    float* __restrict__ bf_q, float* __restrict__ bf_p,
    const int* __restrict__ flbk_cnt, const u64* __restrict__ flbkQ,
    u16* __restrict__ nbr_exp, int* __restrict__ nbr_loc,
    int* __restrict__ cnt_exp, int* __restrict__ cnt_loc,
    const float* __restrict__ emb_loc, _Float16* __restrict__ Ylh,
    const float* __restrict__ W1l_of)
{
  const int lane = threadIdx.x & 63;
  const int w = threadIdx.x >> 6;
  const float* dW1a = dW1;
  const float* dW1b = dW1 + H * H;
  if (blockIdx.x < 4) {
    const float* A; const float* B; float* C;
    switch (blockIdx.x) {
      case 0:  A = W2r_of;  B = dW1b; C = Wf_q;  break;
      case 1:  A = W2l_of;  B = dW1b; C = Wf_y2; break;
      case 2:  A = W2l_rev; B = dW1a; C = Wf_t2; break;
      default: A = W2r_rev; B = dW1a; C = Wf_p;  break;
    }
    float b[H];
#pragma unroll
    for (int k = 0; k < H; k++) b[k] = B[k * H + lane];
    for (int r = w * 16; r < w * 16 + 16; r++) {
      const float xv = A[r * H + lane];
      float a0 = 0.f, a1 = 0.f;
#pragma unroll
      for (int k = 0; k < H; k += 2) {
        a0 += bcastf(xv, k)     * b[k];
        a1 += bcastf(xv, k + 1) * b[k + 1];
      }
      C[r * H + lane] = a0 + a1;
    }
  } else if (blockIdx.x == 4) {
    if (w < 2) {
      const float* bv_src = (w == 0) ? b2_of : b2_rev;
      const float* B      = (w == 0) ? dW1b  : dW1a;
      float* o            = (w == 0) ? bf_q  : bf_p;
      float wk[H];
#pragma unroll
      for (int k = 0; k < H; k++) wk[k] = B[k * H + lane];
      const float bv = bv_src[lane];
      float a = 0.f;
#pragma unroll
      for (int k = 0; k < H; k++) a += bcastf(bv, k) * wk[k];
      o[lane] = a;
    }
  } else if (blockIdx.x == 5) {
    // drain fallback queue (rare Poisson-tail edges; keeps fill exact)
    const int n = min(*flbk_cnt, FCAP);
    for (int i = threadIdx.x; i < n; i += 256) {
      const u64 rec = flbkQ[i];
      const int node = (int)((rec >> 32) & 0x3FFFF);
      const int val  = (int)(rec & 0x3FFFF);
      if ((rec >> 63) == 0) {
        int pos = atomicAdd(&cnt_exp[node], 1);
        if (pos < PAD_E) nbr_exp[(long)node * PAD_E + pos] = (u16)val;
      } else {
        int pos = atomicAdd(&cnt_loc[node], 1);
        if (pos < PAD_L) nbr_loc[(long)node * PAD_L + pos] = val;
      }
    }
  } else {
    // dense: Ylh = emb_loc @ W1l_of (fp16 out), grid-stride 4 rows/wave
    float wreg[H];
#pragma unroll
    for (int k = 0; k < H; k++) wreg[k] = W1l_of[k * H + lane];
    const int gw2 = (blockIdx.x - 6) * 4 + w;       // 0..4999
    for (int r = gw2; r < NLOC; r += 5000) {
      const float xv = emb_loc[(long)r * H + lane];
      float a0 = 0.f, a1 = 0.f;
#pragma unroll
      for (int k = 0; k < H; k += 2) {
        a0 += bcastf(xv, k)     * wreg[k];
        a1 += bcastf(xv, k + 1) * wreg[k + 1];
      }
      Ylh[(long)r * H + lane] = (_Float16)(a0 + a1);
    }
  }
}

// out16 = x @ W (no bias); fp32 in, fp16 out.
__global__ __launch_bounds__(256, 4) void dense_linear_kernel(
    const float* __restrict__ x, _Float16* __restrict__ out16,
    const float* __restrict__ W, int n)
{
  const int lane = threadIdx.x & 63;
  const int gw = (blockIdx.x * 256 + threadIdx.x) >> 6;
  const int nw = (gridDim.x * 256) >> 6;
  float w[H];
#pragma unroll
  for (int k = 0; k < H; k++) w[k] = W[k * H + lane];
  for (int i = gw; i < n; i += nw) {
    const float xv = x[i * H + lane];
    float a0 = 0.f, a1 = 0.f;
#pragma unroll
    for (int k = 0; k < H; k += 2) {
      a0 += bcastf(xv, k)     * w[k];
      a1 += bcastf(xv, k + 1) * w[k + 1];
    }
    out16[i * H + lane] = (_Float16)(a0 + a1);
  }
}

// Exp-side MFMA pass (dual-B, optional gather/bias/relu). Block = 16 rows.
// r5: r3's proven branch-free unroll-4 gather loop; keeps r4's safe wins
// only (cnt/id prefetch, hoisted vector A-loads, Gs stride 68).
__global__ __launch_bounds__(256, 4) void mfma_pass_kernel(
    const u16* __restrict__ nbr, const int* __restrict__ cnt,
    const _Float16* __restrict__ y,
    const float* a32, const _Float16* a16,
    _Float16* out1, const float* __restrict__ W1,
    const float* __restrict__ bias, int relu,
    _Float16* out2, const float* __restrict__ W2)
{
  const int w = threadIdx.x >> 6;
  const int lane = threadIdx.x & 63;
  const int q = lane >> 4;
  const int cidx = lane & 15;
  const int rb = blockIdx.x * 16;

  __shared__ float Gs[16 * 68];

  f16x8 b1lo, b1hi, b2lo, b2hi;
#pragma unroll
  for (int j = 0; j < 8; j++) {
    b1lo[j] = (_Float16)W1[(q * 8 + j) * H + w * 16 + cidx];
    b1hi[j] = (_Float16)W1[(32 + q * 8 + j) * H + w * 16 + cidx];
  }
  if (out2) {
#pragma unroll
    for (int j = 0; j < 8; j++) {
      b2lo[j] = (_Float16)W2[(q * 8 + j) * H + w * 16 + cidx];
      b2hi[j] = (_Float16)W2[(32 + q * 8 + j) * H + w * 16 + cidx];
    }
  }

  // A-fragment load hoisted above the gather (independent; overlaps latency)
  f16x8 a0, a1;
  if (a16) {
    const _Float16* ar = a16 + (long)(rb + cidx) * H;
    a0 = *(const f16x8*)(ar + q * 8);
    a1 = *(const f16x8*)(ar + 32 + q * 8);
  } else {
    const float* ar = a32 + (long)(rb + cidx) * H;
    f32x4 v0 = *(const f32x4*)(ar + q * 8);
    f32x4 v1 = *(const f32x4*)(ar + q * 8 + 4);
    f32x4 v2 = *(const f32x4*)(ar + 32 + q * 8);
    f32x4 v3 = *(const f32x4*)(ar + 32 + q * 8 + 4);
#pragma unroll
    for (int j = 0; j < 4; j++) {
      a0[j] = (_Float16)v0[j];
      a0[j + 4] = (_Float16)v1[j];
      a1[j] = (_Float16)v2[j];
      a1[j + 4] = (_Float16)v3[j];
    }
  }

  if (y) {
    const int i0r = rb + w * 4;
    int c4[4];
#pragma unroll
    for (int rr = 0; rr < 4; rr++) c4[rr] = cnt[i0r + rr];
    int id4[4];
#pragma unroll
    for (int rr = 0; rr < 4; rr++) {
      const int c = min(c4[rr], PAD_E);
      id4[rr] = (lane < c) ? (int)nbr[(long)(i0r + rr) * PAD_E + lane] : 0;
    }
#pragma unroll
    for (int rr = 0; rr < 4; rr++) {
      const int cc = min(c4[rr], PAD_E);
      const int id = id4[rr];
      float s0 = 0.f, s1 = 0.f, s2 = 0.f, s3 = 0.f;
      int k = 0;
      const int m4 = cc & ~3;
      for (; k < m4; k += 4) {
        const int i0 = bcasti(id, k), i1 = bcasti(id, k + 1),
                  i2 = bcasti(id, k + 2), i3 = bcasti(id, k + 3);
        s0 += (float)y[(long)i0 * H + lane];
        s1 += (float)y[(long)i1 * H + lane];
        s2 += (float)y[(long)i2 * H + lane];
        s3 += (float)y[(long)i3 * H + lane];
      }
      for (; k < cc; k++) s0 += (float)y[(long)bcasti(id, k) * H + lane];
      Gs[(w * 4 + rr) * 68 + lane] =
          ((s0 + s1) + (s2 + s3)) / fmaxf((float)c4[rr], 1.0f);
    }
  }

  f32x4 acc1 = {0.f, 0.f, 0.f, 0.f};
  acc1 = __builtin_amdgcn_mfma_f32_16x16x32_f16(a0, b1lo, acc1, 0, 0, 0);
  acc1 = __builtin_amdgcn_mfma_f32_16x16x32_f16(a1, b1hi, acc1, 0, 0, 0);
  f32x4 acc2 = {0.f, 0.f, 0.f, 0.f};
  if (out2) {
    acc2 = __builtin_amdgcn_mfma_f32_16x16x32_f16(a0, b2lo, acc2, 0, 0, 0);
    acc2 = __builtin_amdgcn_mfma_f32_16x16x32_f16(a1, b2hi, acc2, 0, 0, 0);
  }

  const float bj = bias ? bias[w * 16 + cidx] : 0.f;
  __syncthreads();   // Gs ready; all A loads drained before in-place stores
#pragma unroll
  for (int reg = 0; reg < 4; reg++) {
    const int r = q * 4 + reg;
    float v = acc1[reg] + bj;
    if (y) v += Gs[r * 68 + w * 16 + cidx];
    if (relu) v = fmaxf(v, 0.f);
    out1[(long)(rb + r) * H + w * 16 + cidx] = (_Float16)v;
    if (out2)
      out2[(long)(rb + r) * H + w * 16 + cidx] = (_Float16)acc2[reg];
  }
}

// Loc side: out = mean-gather(fp16 T rows) + x @ Wr + bias (opt relu).
// r5: r3's proven branch-free single-row loop, deepened to 8 accumulators
// (m8/m4/tail chunks — no per-load conditionals), grid 2048 blocks.
__global__ __launch_bounds__(256, 4) void loc_gather_kernel(
    const int* __restrict__ nbr, const int* __restrict__ cnt,
    const _Float16* __restrict__ T, const float* __restrict__ x,
    float* __restrict__ out32, _Float16* __restrict__ out16,
    const float* __restrict__ Wr, const float* __restrict__ bias,
    int n, int relu)
{
  const int lane = threadIdx.x & 63;
  const int gw = (blockIdx.x * 256 + threadIdx.x) >> 6;
  const int nw = (gridDim.x * 256) >> 6;
  float wr[H];
#pragma unroll
  for (int k = 0; k < H; k++) wr[k] = Wr[k * H + lane];
  const float bj = bias[lane];
  for (int i = gw; i < n; i += nw) {
    const int c = cnt[i];
    const int cc = min(c, PAD_L);
    const int* nb = nbr + (long)i * PAD_L;
    float s0 = 0.f, s1 = 0.f, s2 = 0.f, s3 = 0.f;
    float s4 = 0.f, s5 = 0.f, s6 = 0.f, s7 = 0.f;
    int e = 0;
    while (e < cc) {
      const int m = min(cc - e, 64);
      const int id = (lane < m) ? nb[e + lane] : 0;
      int k = 0;
      const int m8 = m & ~7;
      for (; k < m8; k += 8) {
        const int i0 = bcasti(id, k),     i1 = bcasti(id, k + 1),
                  i2 = bcasti(id, k + 2), i3 = bcasti(id, k + 3),
                  i4 = bcasti(id, k + 4), i5 = bcasti(id, k + 5),
                  i6 = bcasti(id, k + 6), i7 = bcasti(id, k + 7);
        s0 += (float)T[(long)i0 * H + lane];
        s1 += (float)T[(long)i1 * H + lane];
        s2 += (float)T[(long)i2 * H + lane];
        s3 += (float)T[(long)i3 * H + lane];
        s4 += (float)T[(long)i4 * H + lane];
        s5 += (float)T[(long)i5 * H + lane];
        s6 += (float)T[(long)i6 * H + lane];
        s7 += (float)T[(long)i7 * H + lane];
      }
      const int m4 = m & ~3;
      for (; k < m4; k += 4) {
        const int i0 = bcasti(id, k), i1 = bcasti(id, k + 1),
                  i2 = bcasti(id, k + 2), i3 = bcasti(id, k + 3);
        s0 += (float)T[(long)i0 * H + lane];
        s1 += (float)T[(long)i1 * H + lane];
        s2 += (float)T[(long)i2 * H + lane];
        s3 += (float)T[(long)i3 * H + lane];
      }
      for (; k < m; k++) s0 += (float)T[(long)bcasti(id, k) * H + lane];
      e += m;
    }
    const float agg = (((s0 + s1) + (s2 + s3)) + ((s4 + s5) + (s6 + s7))) /
                      fmaxf((float)c, 1.0f);
    const float xv = x[(long)i * H + lane];
    float a0 = 0.f, a1 = 0.f;
#pragma unroll
    for (int k = 0; k < H; k += 2) {
      a0 += bcastf(xv, k)     * wr[k];
      a1 += bcastf(xv, k + 1) * wr[k + 1];
    }
    float acc = agg + bj + a0 + a1;
    if (relu) acc = fmaxf(acc, 0.0f);
    if (out32) out32[(long)i * H + lane] = acc;
    else       out16[(long)i * H + lane] = (_Float16)acc;
  }
}

// out[e] = sum_j relu(P[r,j] + Q[c,j] + db1[j]) * dW2[j] + db2  (P,Q fp16)
__global__ __launch_bounds__(256, 4) void edge_kernel(
    const int* __restrict__ row, const int* __restrict__ col,
    const _Float16* __restrict__ P, const _Float16* __restrict__ Q,
    const float* __restrict__ db1, const float* __restrict__ dW2,
    const float* __restrict__ db2, float* __restrict__ out)
{
  const int lane = threadIdx.x & 63;
  const int gw = (blockIdx.x * 256 + threadIdx.x) >> 6;
  const int nw = (gridDim.x * 256) >> 6;
  const float bj = db1[lane];
  const float w2 = dW2[lane];
  const float b2 = db2[0];
  for (int e = gw * 4; e < NL; e += nw * 4) {
    const int n4 = min(NL - e, 4);
    float h[4];
#pragma unroll
    for (int k = 0; k < 4; k++) {
      if (k < n4) {
        const int r = row[e + k], c = col[e + k];
        const float p = (float)P[(long)r * H + lane];
        const float q = (float)Q[(long)c * H + lane];
        h[k] = fmaxf(p + q + bj, 0.0f) * w2;
      } else h[k] = 0.f;
    }
#pragma unroll
    for (int off = 1; off < 64; off <<= 1) {
#pragma unroll
      for (int k = 0; k < 4; k++) h[k] += __shfl_xor(h[k], off);
    }
    if (lane == 0) {
#pragma unroll
      for (int k = 0; k < 4; k++)
        if (k < n4) out[e + k] = h[k] + b2;
    }
  }
}

extern "C" void kernel_launch(void* const* d_in, const int* in_sizes, int n_in,
                              void* d_out, int out_size, void* d_ws, size_t ws_size,
                              hipStream_t stream) {
  const float* emb_loc = (const float*)d_in[0];
  const float* emb_exp = (const float*)d_in[1];
  const float* W1l_of  = (const float*)d_in[2];
  const float* b1_of   = (const float*)d_in[3];
  const float* W1r_of  = (const float*)d_in[4];
  const float* W1l_rev = (const float*)d_in[5];
  const float* b1_rev  = (const float*)d_in[6];
  const float* W1r_rev = (const float*)d_in[7];
  const float* W2l_of  = (const float*)d_in[8];
  const float* b2_of   = (const float*)d_in[9];
  const float* W2r_of  = (const float*)d_in[10];
  const float* W2l_rev = (const float*)d_in[11];
  const float* b2_rev  = (const float*)d_in[12];
  const float* W2r_rev = (const float*)d_in[13];
  const float* dW1     = (const float*)d_in[14];
  const float* db1     = (const float*)d_in[15];
  const float* dW2     = (const float*)d_in[16];
  const float* db2     = (const float*)d_in[17];
  const int*   edge_of = (const int*)d_in[18];
  const int*   eli     = (const int*)d_in[20];

  const int* src = edge_of;
  const int* dst = edge_of + NE;
  const int* row = eli;
  const int* col = eli + NL;

  if (ws_size < WS_NEED) return;

  char* ws = (char*)d_ws;
  int*            cnt_loc = (int*)(ws);
  int*            cnt_exp = (int*)(ws + 80000);
  int*            nbr_loc = (int*)(ws + 880064);
  unsigned short* nbr_exp = (unsigned short*)(ws + 11120064);
  _Float16*       Ylh     = (_Float16*)(ws + 23920064);
  _Float16*       Y2fh    = (_Float16*)(ws + 26480064);
  float*          z_loc   = (float*)(ws + 29040064);
  _Float16*       PH      = (_Float16*)(ws + 34160064);
  _Float16*       ZE      = (_Float16*)(ws + 39280064);
  _Float16*       TH      = (_Float16*)(ws + 64880064);
  // fill-time aliases over the TH region (dead until mfma pass #1)
  u32*            expQ    = (u32*)(ws + 64880064);
  u32*            locQ    = (u32*)(ws + 72220096);
  int*            qcnt    = (int*)(ws + 79551936);
  int*            flbk    = (int*)(ws + 79553552);
  u64*            flbkQ   = (u64*)(ws + 79554048);
  float*          Wf_q    = (float*)(ws + 90480064);
  float*          Wf_y2   = (float*)(ws + 90496448);
  float*          Wf_t2   = (float*)(ws + 90512832);
  float*          Wf_p    = (float*)(ws + 90529216);
  float*          bf_q    = (float*)(ws + 90545600);
  float*          bf_p    = (float*)(ws + 90545856);
  float*          out     = (float*)d_out;

  // zero queue counters + fallback counter only
  (void)hipMemsetAsync(ws + 79551936, 0, 2048, stream);

  // ---- CSR fill: bin -> build (full-line writes) ----
  bin_kernel<<<NBIN, 256, 0, stream>>>(src, dst, expQ, locQ, qcnt, flbk, flbkQ);
  build_kernel<<<NBE + NBL, 256, 0, stream>>>(expQ, locQ, qcnt,
      nbr_exp, nbr_loc, cnt_exp, cnt_loc);
  // fold + fallback drain + dense#1 in one launch (grid-stride dense)
  prep_kernel<<<1256, 256, 0, stream>>>(W2r_of, W2l_of, W2l_rev, W2r_rev,
                                        dW1, b2_of, b2_rev,
                                        Wf_q, Wf_y2, Wf_t2, Wf_p, bf_q, bf_p,
                                        flbk, flbkQ, nbr_exp, nbr_loc,
                                        cnt_exp, cnt_loc,
                                        emb_loc, Ylh, W1l_of);

  // ---- layer 1 ----
  // passA: z_exph = relu(emb_exp@W1r_of + gatherE(Ylh) + b1_of); T1h = emb_exp@W1l_rev
  mfma_pass_kernel<<<NEXP / 16, 256, 0, stream>>>(nbr_exp, cnt_exp, Ylh,
      emb_exp, (const _Float16*)nullptr, ZE, W1r_of, b1_of, 1, TH, W1l_rev);
  loc_gather_kernel<<<2048, 256, 0, stream>>>(nbr_loc, cnt_loc, TH,
      emb_loc, z_loc, (_Float16*)nullptr, W1r_rev, b1_rev, NLOC, 1);

  // ---- layer 2 + decoder transforms (folded: no relu on layer 2) ----
  dense_linear_kernel<<<1280, 256, 0, stream>>>(z_loc, Y2fh, Wf_y2, NLOC);
  // passB: Qh = z_exph@Wf_q + gatherE(Y2fh) + bf_q (in-place over ZE);
  //        T2'h = z_exph@Wf_t2 (over TH; T1h consumed)
  mfma_pass_kernel<<<NEXP / 16, 256, 0, stream>>>(nbr_exp, cnt_exp, Y2fh,
      (const float*)nullptr, ZE, ZE, Wf_q, bf_q, 0, TH, Wf_t2);
  // PH = gatherL(T2'h) + z_loc@Wf_p + bf_p   (decoder-left, folded, fp16 out)
  loc_gather_kernel<<<2048, 256, 0, stream>>>(nbr_loc, cnt_loc, TH,
      z_loc, (float*)nullptr, PH, Wf_p, bf_p, NLOC, 0);

  // ---- decoder edge pass ----
  edge_kernel<<<2048, 256, 0, stream>>>(row, col, PH, ZE,
                                        db1, dW2, db2, out);
}

// Round 6
// 502.286 us; speedup vs baseline: 1.4004x; 1.0215x over previous
//
#include <hip/hip_runtime.h>

#define H 64
#define NE 1500000
#define NLOC 20000
#define NEXP 200000
#define NL 400000
#define PAD_E 32
#define PAD_L 128

// ---- bucket-sort fill geometry ----
#define EB 896                        // experts per bucket (row LDS = 56KB)
#define NBE 224                       // ceil(200000/896)
#define LB 112                        // locs per bucket (row LDS = 56KB)
#define NBL 179                       // ceil(20000/112)
#define BIN_CHUNK 2048
#define NBIN ((NE + BIN_CHUNK - 1) / BIN_CHUNK)   // 733
#define EBSLOT 28                     // LDS slots per exp bucket per block
#define LBSLOT 32                     // LDS slots per loc bucket per block
#define ECAP 8192                     // exp queue capacity (lam 6696, +18 sigma)
#define LCAP 10240                    // loc queue capacity (lam 8380, +20 sigma)
#define FCAP 4096                     // fallback queue

// ---- workspace layout (bytes) ----
// cnt_loc [0,80000)  cnt_exp [80000,880000)
// nbr_loc [880064,11120064)  nbr_exp(u16) [11120064,23920064)
// Ylh(f16)  [23920064,26480064)   Y2fh(f16) [26480064,29040064)
// z_loc(f32)[29040064,34160064)   PH(f16)   [34160064,36720064)
//   fp16-transposed MFMA B weights (in the PH..ZE hole):
//   W1rT16 [36720064,+8192) W1lrT16 [36728256,+8192)
//   WfqT16 [36736448,+8192) Wft2T16 [36744640,+8192)
// ZE(f16)   [39280064,64880064)   z_exph -> Qh (in-place)
// TH(f16)   [64880064,90480064)   T1h -> T2'h
//   (aliased pre-mfma: expQ [64880064,72220096) locQ [72220096,79551936)
//    qcnt [79551936,+1612) flbk_cnt [79553552) flbkQ [79554048,+32768))
// Wf_q [90480064) Wf_y2 [90496448) Wf_t2 [90512832) Wf_p [90529216)
// bf_q [90545600) bf_p [90545856)
#define WS_NEED 90546112ULL

typedef int vint4 __attribute__((ext_vector_type(4)));
typedef _Float16 f16x8 __attribute__((ext_vector_type(8)));
typedef _Float16 f16x4 __attribute__((ext_vector_type(4)));
typedef float f32x4 __attribute__((ext_vector_type(4)));
typedef unsigned int u32;
typedef unsigned short u16;
typedef unsigned long long u64;

__device__ __forceinline__ float bcastf(float v, int k) {
  return __int_as_float(__builtin_amdgcn_readlane(__float_as_int(v), k));
}
__device__ __forceinline__ int bcasti(int v, int k) {
  return __builtin_amdgcn_readlane(v, k);
}
__device__ __forceinline__ int sel4(int g, int n0, int n1, int n2, int n3) {
  return (g & 2) ? ((g & 1) ? n3 : n2) : ((g & 1) ? n1 : n0);
}

// ---------------- bucket-sort fill, pass 1: bin edges ----------------
__global__ __launch_bounds__(256) void bin_kernel(
    const int* __restrict__ src, const int* __restrict__ dst,
    u32* __restrict__ expQ, u32* __restrict__ locQ,
    int* __restrict__ qcnt, int* __restrict__ flbk_cnt,
    u64* __restrict__ flbkQ)
{
  __shared__ u32 eb[NBE * EBSLOT];   // 25088 B
  __shared__ u32 lb[NBL * LBSLOT];   // 22912 B
  __shared__ int ec[NBE], lc[NBL], ebase[NBE], lbase[NBL];  // 3224 B

  const int tid = threadIdx.x;
  for (int i = tid; i < NBE; i += 256) ec[i] = 0;
  for (int i = tid; i < NBL; i += 256) lc[i] = 0;
  __syncthreads();

  const long base = (long)blockIdx.x * BIN_CHUNK + tid * 8;
  if (base < NE) {   // NE % 8 == 0, so full 8-edge packet
    vint4 s0 = __builtin_nontemporal_load((const vint4*)(src + base));
    vint4 s1 = __builtin_nontemporal_load((const vint4*)(src + base + 4));
    vint4 d0 = __builtin_nontemporal_load((const vint4*)(dst + base));
    vint4 d1 = __builtin_nontemporal_load((const vint4*)(dst + base + 4));
    int ss[8] = {s0.x, s0.y, s0.z, s0.w, s1.x, s1.y, s1.z, s1.w};
    int dd[8] = {d0.x, d0.y, d0.z, d0.w, d1.x, d1.y, d1.z, d1.w};
#pragma unroll
    for (int k = 0; k < 8; k++) {
      const u32 d = (u32)dd[k], s = (u32)ss[k];
      {  // exp side: bucket by dst
        const u32 b = d / (u32)EB;
        const int pos = atomicAdd(&ec[b], 1);
        if (pos < EBSLOT) {
          eb[b * EBSLOT + pos] = ((d - b * EB) << 16) | s;
        } else {
          int fi = atomicAdd(flbk_cnt, 1);
          if (fi < FCAP) flbkQ[fi] = ((u64)d << 32) | (u64)s;   // side bit 0
        }
      }
      {  // loc side: bucket by src
        const u32 b = s / (u32)LB;
        const int pos = atomicAdd(&lc[b], 1);
        if (pos < LBSLOT) {
          lb[b * LBSLOT + pos] = ((s - b * LB) << 18) | d;
        } else {
          int fi = atomicAdd(flbk_cnt, 1);
          if (fi < FCAP) flbkQ[fi] = (1ULL << 63) | ((u64)s << 32) | (u64)d;
        }
      }
    }
  }
  __syncthreads();

  // reserve queue space (one global atomic per non-empty bucket, all parallel)
  for (int i = tid; i < NBE; i += 256) {
    const int c = min(ec[i], EBSLOT);
    ebase[i] = c ? atomicAdd(&qcnt[i], c) : 0;
  }
  for (int i = tid; i < NBL; i += 256) {
    const int c = min(lc[i], LBSLOT);
    lbase[i] = c ? atomicAdd(&qcnt[NBE + i], c) : 0;
  }
  __syncthreads();

  // flush dense runs (wave per bucket stripe)
  const int wid = tid >> 6, ln = tid & 63;
  for (int b = wid; b < NBE; b += 4) {
    const int c = min(ec[b], EBSLOT);
    if (ln < c) {
      const int idx = ebase[b] + ln;
      const u32 r = eb[b * EBSLOT + ln];
      if (idx < ECAP) {
        expQ[(long)b * ECAP + idx] = r;
      } else {
        int fi = atomicAdd(flbk_cnt, 1);
        if (fi < FCAP)
          flbkQ[fi] = ((u64)(b * EB + (r >> 16)) << 32) | (u64)(r & 0xFFFF);
      }
    }
  }
  for (int b = wid; b < NBL; b += 4) {
    const int c = min(lc[b], LBSLOT);
    if (ln < c) {
      const int idx = lbase[b] + ln;
      const u32 r = lb[b * LBSLOT + ln];
      if (idx < LCAP) {
        locQ[(long)b * LCAP + idx] = r;
      } else {
        int fi = atomicAdd(flbk_cnt, 1);
        if (fi < FCAP)
          flbkQ[fi] = (1ULL << 63) | ((u64)(b * LB + (r >> 18)) << 32) |
                      (u64)(r & 0x3FFFF);
      }
    }
  }
}

// ---------------- bucket-sort fill, pass 2: build padded CSR ----------------
__global__ __launch_bounds__(256) void build_kernel(
    const u32* __restrict__ expQ, const u32* __restrict__ locQ,
    const int* __restrict__ qcnt,
    u16* __restrict__ nbr_exp, int* __restrict__ nbr_loc,
    int* __restrict__ cnt_exp, int* __restrict__ cnt_loc)
{
  __shared__ char ldsraw[60928];
  const int tid = threadIdx.x;
  if (blockIdx.x < NBE) {
    const int b = blockIdx.x;
    u16* rows = (u16*)ldsraw;                 // EB*PAD_E u16 = 57344 B
    int* cnts = (int*)(ldsraw + 57344);       // EB ints  = 3584 B
    for (int i = tid; i < EB; i += 256) cnts[i] = 0;
    __syncthreads();
    const int n = min(qcnt[b], ECAP);
    for (int i = tid; i < n; i += 256) {
      const u32 r = expQ[(long)b * ECAP + i];
      const int nl = (int)(r >> 16);
      const int pos = atomicAdd(&cnts[nl], 1);
      if (pos < PAD_E) rows[nl * PAD_E + pos] = (u16)(r & 0xFFFF);
    }
    __syncthreads();
    const int node0 = b * EB;
    const int nn = min(EB, NEXP - node0);
    u32* grows = (u32*)(nbr_exp + (long)node0 * PAD_E);
    const u32* lrows = (const u32*)rows;
    for (int j = tid; j < nn * (PAD_E / 2); j += 256) grows[j] = lrows[j];
    for (int i = tid; i < nn; i += 256) cnt_exp[node0 + i] = cnts[i];
  } else {
    const int b = blockIdx.x - NBE;
    int* rows = (int*)ldsraw;                 // LB*PAD_L int = 57344 B
    int* cnts = (int*)(ldsraw + 57344);       // LB ints = 448 B
    for (int i = tid; i < LB; i += 256) cnts[i] = 0;
    __syncthreads();
    const int n = min(qcnt[NBE + b], LCAP);
    for (int i = tid; i < n; i += 256) {
      const u32 r = locQ[(long)b * LCAP + i];
      const int sl = (int)(r >> 18);
      const int pos = atomicAdd(&cnts[sl], 1);
      if (pos < PAD_L) rows[sl * PAD_L + pos] = (int)(r & 0x3FFFF);
    }
    __syncthreads();
    const int node0 = b * LB;
    const int nn = min(LB, NLOC - node0);
    int* grows = nbr_loc + (long)node0 * PAD_L;
    for (int j = tid; j < nn * PAD_L; j += 256) grows[j] = rows[j];
    for (int i = tid; i < nn; i += 256) cnt_loc[node0 + i] = cnts[i];
  }
}

// prep_kernel: fold (blk 0-4, with fp16-transposed copies of Wf_q/Wf_t2) +
// fallback drain (blk 5) + fp16 transpose of W1r_of/W1l_rev (blk 6-7) +
// dense Ylh grid-stride (blk >=8).
__global__ __launch_bounds__(256) void prep_kernel(
    const float* __restrict__ W2r_of, const float* __restrict__ W2l_of,
    const float* __restrict__ W2l_rev, const float* __restrict__ W2r_rev,
    const float* __restrict__ dW1, const float* __restrict__ b2_of,
    const float* __restrict__ b2_rev,
    float* __restrict__ Wf_q, float* __restrict__ Wf_y2,
    float* __restrict__ Wf_t2, float* __restrict__ Wf_p,
    float* __restrict__ bf_q, float* __restrict__ bf_p,
    const int* __restrict__ flbk_cnt, const u64* __restrict__ flbkQ,
    u16* __restrict__ nbr_exp, int* __restrict__ nbr_loc,
    int* __restrict__ cnt_exp, int* __restrict__ cnt_loc,
    const float* __restrict__ emb_loc, _Float16* __restrict__ Ylh,
    const float* __restrict__ W1l_of,
    const float* __restrict__ W1r_of, const float* __restrict__ W1l_rev,
    _Float16* __restrict__ W1rT16, _Float16* __restrict__ W1lrT16,
    _Float16* __restrict__ WfqT16, _Float16* __restrict__ Wft2T16)
{
  const int lane = threadIdx.x & 63;
  const int w = threadIdx.x >> 6;
  const float* dW1a = dW1;
  const float* dW1b = dW1 + H * H;
  if (blockIdx.x < 4) {
    const float* A; const float* B; float* C; _Float16* CT;
    switch (blockIdx.x) {
      case 0:  A = W2r_of;  B = dW1b; C = Wf_q;  CT = WfqT16;  break;
      case 1:  A = W2l_of;  B = dW1b; C = Wf_y2; CT = nullptr; break;
      case 2:  A = W2l_rev; B = dW1a; C = Wf_t2; CT = Wft2T16; break;
      default: A = W2r_rev; B = dW1a; C = Wf_p;  CT = nullptr; break;
    }
    float b[H];
#pragma unroll
    for (int k = 0; k < H; k++) b[k] = B[k * H + lane];
    for (int r = w * 16; r < w * 16 + 16; r++) {
      const float xv = A[r * H + lane];
      float a0 = 0.f, a1 = 0.f;
#pragma unroll
      for (int k = 0; k < H; k += 2) {
        a0 += bcastf(xv, k)     * b[k];
        a1 += bcastf(xv, k + 1) * b[k + 1];
      }
      const float val = a0 + a1;
      C[r * H + lane] = val;
      if (CT) CT[(long)lane * H + r] = (_Float16)val;   // transposed fp16
    }
  } else if (blockIdx.x == 4) {
    if (w < 2) {
      const float* bv_src = (w == 0) ? b2_of : b2_rev;
      const float* B      = (w == 0) ? dW1b  : dW1a;
      float* o            = (w == 0) ? bf_q  : bf_p;
      float wk[H];
#pragma unroll
      for (int k = 0; k < H; k++) wk[k] = B[k * H + lane];
      const float bv = bv_src[lane];
      float a = 0.f;
#pragma unroll
      for (int k = 0; k < H; k++) a += bcastf(bv, k) * wk[k];
      o[lane] = a;
    }
  } else if (blockIdx.x == 5) {
    // drain fallback queue (rare Poisson-tail edges; keeps fill exact)
    const int n = min(*flbk_cnt, FCAP);
    for (int i = threadIdx.x; i < n; i += 256) {
      const u64 rec = flbkQ[i];
      const int node = (int)((rec >> 32) & 0x3FFFF);
      const int val  = (int)(rec & 0x3FFFF);
      if ((rec >> 63) == 0) {
        int pos = atomicAdd(&cnt_exp[node], 1);
        if (pos < PAD_E) nbr_exp[(long)node * PAD_E + pos] = (u16)val;
      } else {
        int pos = atomicAdd(&cnt_loc[node], 1);
        if (pos < PAD_L) nbr_loc[(long)node * PAD_L + pos] = val;
      }
    }
  } else if (blockIdx.x < 8) {
    // fp16 transpose of input weights for MFMA B-fragment vector loads
    const float* S = (blockIdx.x == 6) ? W1r_of : W1l_rev;
    _Float16* D    = (blockIdx.x == 6) ? W1rT16 : W1lrT16;
    for (int k = w * 16; k < w * 16 + 16; k++)
      D[(long)lane * H + k] = (_Float16)S[(long)k * H + lane];
  } else {
    // dense: Ylh = emb_loc @ W1l_of (fp16 out), grid-stride 4 rows/wave
    float wreg[H];
#pragma unroll
    for (int k = 0; k < H; k++) wreg[k] = W1l_of[k * H + lane];
    const int gw2 = (blockIdx.x - 8) * 4 + w;       // 0..4999
    for (int r = gw2; r < NLOC; r += 5000) {
      const float xv = emb_loc[(long)r * H + lane];
      float a0 = 0.f, a1 = 0.f;
#pragma unroll
      for (int k = 0; k < H; k += 2) {
        a0 += bcastf(xv, k)     * wreg[k];
        a1 += bcastf(xv, k + 1) * wreg[k + 1];
      }
      Ylh[(long)r * H + lane] = (_Float16)(a0 + a1);
    }
  }
}

// out16 = x @ W (no bias); fp32 in, fp16 out.
__global__ __launch_bounds__(256, 4) void dense_linear_kernel(
    const float* __restrict__ x, _Float16* __restrict__ out16,
    const float* __restrict__ W, int n)
{
  const int lane = threadIdx.x & 63;
  const int gw = (blockIdx.x * 256 + threadIdx.x) >> 6;
  const int nw = (gridDim.x * 256) >> 6;
  float w[H];
#pragma unroll
  for (int k = 0; k < H; k++) w[k] = W[k * H + lane];
  for (int i = gw; i < n; i += nw) {
    const float xv = x[i * H + lane];
    float a0 = 0.f, a1 = 0.f;
#pragma unroll
    for (int k = 0; k < H; k += 2) {
      a0 += bcastf(xv, k)     * w[k];
      a1 += bcastf(xv, k + 1) * w[k + 1];
    }
    out16[i * H + lane] = (_Float16)(a0 + a1);
  }
}

// Exp-side MFMA pass (dual-B, optional gather/bias/relu). Block = 16 rows.
// r6: quad-row gather — one wave-load (f16x4/lane) fetches FOUR neighbor
// rows (group g = lane>>4 selects neighbor, lane&15 the 8B row slice).
// Loads per row: cc -> ceil(cc/4). Branch-free: clamped bcasti + masked fma
// (wave-uniform trip counts). B-fragments from fp16 pre-transposed weights
// (4 vector loads vs 64 scalar f32 loads + cvt).
__global__ __launch_bounds__(256, 4) void mfma_pass_kernel(
    const u16* __restrict__ nbr, const int* __restrict__ cnt,
    const _Float16* __restrict__ y,
    const float* a32, const _Float16* a16,
    _Float16* out1, const _Float16* __restrict__ W1T,
    const float* __restrict__ bias, int relu,
    _Float16* out2, const _Float16* __restrict__ W2T)
{
  const int w = threadIdx.x >> 6;
  const int lane = threadIdx.x & 63;
  const int q = lane >> 4;
  const int cidx = lane & 15;
  const int rb = blockIdx.x * 16;

  __shared__ float Gs[16 * 68];

  const _Float16* bt1 = W1T + (long)(w * 16 + cidx) * H;
  f16x8 b1lo = *(const f16x8*)(bt1 + q * 8);
  f16x8 b1hi = *(const f16x8*)(bt1 + 32 + q * 8);
  f16x8 b2lo, b2hi;
  if (out2) {
    const _Float16* bt2 = W2T + (long)(w * 16 + cidx) * H;
    b2lo = *(const f16x8*)(bt2 + q * 8);
    b2hi = *(const f16x8*)(bt2 + 32 + q * 8);
  }

  // A-fragment load hoisted above the gather (independent; overlaps latency)
  f16x8 a0, a1;
  if (a16) {
    const _Float16* ar = a16 + (long)(rb + cidx) * H;
    a0 = *(const f16x8*)(ar + q * 8);
    a1 = *(const f16x8*)(ar + 32 + q * 8);
  } else {
    const float* ar = a32 + (long)(rb + cidx) * H;
    f32x4 v0 = *(const f32x4*)(ar + q * 8);
    f32x4 v1 = *(const f32x4*)(ar + q * 8 + 4);
    f32x4 v2 = *(const f32x4*)(ar + 32 + q * 8);
    f32x4 v3 = *(const f32x4*)(ar + 32 + q * 8 + 4);
#pragma unroll
    for (int j = 0; j < 4; j++) {
      a0[j] = (_Float16)v0[j];
      a0[j + 4] = (_Float16)v1[j];
      a1[j] = (_Float16)v2[j];
      a1[j + 4] = (_Float16)v3[j];
    }
  }

  if (y) {
    const int i0r = rb + w * 4;
    const int g = lane >> 4;
    const int sub = lane & 15;
    int c4v[4];
#pragma unroll
    for (int rr = 0; rr < 4; rr++) c4v[rr] = cnt[i0r + rr];
    int id4[4];
#pragma unroll
    for (int rr = 0; rr < 4; rr++) {
      const int c = min(c4v[rr], PAD_E);
      id4[rr] = (lane < c) ? (int)nbr[(long)(i0r + rr) * PAD_E + lane] : 0;
    }
#pragma unroll
    for (int rr = 0; rr < 4; rr++) {
      const int cc = min(c4v[rr], PAD_E);
      const int id = id4[rr];
      const int kl = cc - 1;
      float s0 = 0.f, s1 = 0.f, s2 = 0.f, s3 = 0.f;
      for (int k = 0; k < cc; k += 4) {
        const int n0 = bcasti(id, k);
        const int n1 = bcasti(id, min(k + 1, kl));
        const int n2 = bcasti(id, min(k + 2, kl));
        const int n3 = bcasti(id, min(k + 3, kl));
        const int ns = sel4(g, n0, n1, n2, n3);
        const f16x4 v = *(const f16x4*)(y + (long)ns * H + sub * 4);
        const float msk = (k + g < cc) ? 1.0f : 0.0f;
        s0 = fmaf(msk, (float)v[0], s0);
        s1 = fmaf(msk, (float)v[1], s1);
        s2 = fmaf(msk, (float)v[2], s2);
        s3 = fmaf(msk, (float)v[3], s3);
      }
      s0 += __shfl_xor(s0, 16); s0 += __shfl_xor(s0, 32);
      s1 += __shfl_xor(s1, 16); s1 += __shfl_xor(s1, 32);
      s2 += __shfl_xor(s2, 16); s2 += __shfl_xor(s2, 32);
      s3 += __shfl_xor(s3, 16); s3 += __shfl_xor(s3, 32);
      const float inv = 1.0f / fmaxf((float)c4v[rr], 1.0f);
      if (lane < 16) {
        float* gp = &Gs[(w * 4 + rr) * 68 + 4 * lane];
        gp[0] = s0 * inv; gp[1] = s1 * inv;
        gp[2] = s2 * inv; gp[3] = s3 * inv;
      }
    }
  }

  f32x4 acc1 = {0.f, 0.f, 0.f, 0.f};
  acc1 = __builtin_amdgcn_mfma_f32_16x16x32_f16(a0, b1lo, acc1, 0, 0, 0);
  acc1 = __builtin_amdgcn_mfma_f32_16x16x32_f16(a1, b1hi, acc1, 0, 0, 0);
  f32x4 acc2 = {0.f, 0.f, 0.f, 0.f};
  if (out2) {
    acc2 = __builtin_amdgcn_mfma_f32_16x16x32_f16(a0, b2lo, acc2, 0, 0, 0);
    acc2 = __builtin_amdgcn_mfma_f32_16x16x32_f16(a1, b2hi, acc2, 0, 0, 0);
  }

  const float bj = bias ? bias[w * 16 + cidx] : 0.f;
  __syncthreads();   // Gs ready; all A loads drained before in-place stores
#pragma unroll
  for (int reg = 0; reg < 4; reg++) {
    const int r = q * 4 + reg;
    float v = acc1[reg] + bj;
    if (y) v += Gs[r * 68 + w * 16 + cidx];
    if (relu) v = fmaxf(v, 0.f);
    out1[(long)(rb + r) * H + w * 16 + cidx] = (_Float16)v;
    if (out2)
      out2[(long)(rb + r) * H + w * 16 + cidx] = (_Float16)acc2[reg];
  }
}

// Loc side: out = mean-gather(fp16 T rows) + x @ Wr + bias (opt relu).
// r6: twin-quad gather (2 wave-loads fetch 8 neighbor rows per iteration;
// loads per row: cc -> ~cc/8 + cc/8). Masked fma, clamped bcasti, then
// shfl relayout back to lane=col for the dense epilogue.
__global__ __launch_bounds__(256, 4) void loc_gather_kernel(
    const int* __restrict__ nbr, const int* __restrict__ cnt,
    const _Float16* __restrict__ T, const float* __restrict__ x,
    float* __restrict__ out32, _Float16* __restrict__ out16,
    const float* __restrict__ Wr, const float* __restrict__ bias,
    int n, int relu)
{
  const int lane = threadIdx.x & 63;
  const int gw = (blockIdx.x * 256 + threadIdx.x) >> 6;
  const int nw = (gridDim.x * 256) >> 6;
  const int g = lane >> 4;
  const int sub = lane & 15;
  float wr[H];
#pragma unroll
  for (int k = 0; k < H; k++) wr[k] = Wr[k * H + lane];
  const float bj = bias[lane];
  for (int i = gw; i < n; i += nw) {
    const int c = cnt[i];
    const int cc = min(c, PAD_L);
    const int* nb = nbr + (long)i * PAD_L;
    float s0 = 0.f, s1 = 0.f, s2 = 0.f, s3 = 0.f;
    float s4 = 0.f, s5 = 0.f, s6 = 0.f, s7 = 0.f;
    int e = 0;
    while (e < cc) {
      const int m = min(cc - e, 64);
      const int id = (lane < m) ? nb[e + lane] : 0;
      const int ml = m - 1;
      for (int k = 0; k < m; k += 8) {
        const int a0i = bcasti(id, k);
        const int a1i = bcasti(id, min(k + 1, ml));
        const int a2i = bcasti(id, min(k + 2, ml));
        const int a3i = bcasti(id, min(k + 3, ml));
        const int nsA = sel4(g, a0i, a1i, a2i, a3i);
        const f16x4 vA = *(const f16x4*)(T + (long)nsA * H + sub * 4);
        const int b0i = bcasti(id, min(k + 4, ml));
        const int b1i = bcasti(id, min(k + 5, ml));
        const int b2i = bcasti(id, min(k + 6, ml));
        const int b3i = bcasti(id, min(k + 7, ml));
        const int nsB = sel4(g, b0i, b1i, b2i, b3i);
        const f16x4 vB = *(const f16x4*)(T + (long)nsB * H + sub * 4);
        const float mA = (k + g < m) ? 1.0f : 0.0f;
        const float mB = (k + 4 + g < m) ? 1.0f : 0.0f;
        s0 = fmaf(mA, (float)vA[0], s0);
        s1 = fmaf(mA, (float)vA[1], s1);
        s2 = fmaf(mA, (float)vA[2], s2);
        s3 = fmaf(mA, (float)vA[3], s3);
        s4 = fmaf(mB, (float)vB[0], s4);
        s5 = fmaf(mB, (float)vB[1], s5);
        s6 = fmaf(mB, (float)vB[2], s6);
        s7 = fmaf(mB, (float)vB[3], s7);
      }
      e += m;
    }
    s0 += s4; s1 += s5; s2 += s6; s3 += s7;
    s0 += __shfl_xor(s0, 16); s0 += __shfl_xor(s0, 32);
    s1 += __shfl_xor(s1, 16); s1 += __shfl_xor(s1, 32);
    s2 += __shfl_xor(s2, 16); s2 += __shfl_xor(s2, 32);
    s3 += __shfl_xor(s3, 16); s3 += __shfl_xor(s3, 32);
    // relayout 4-col -> lane=col: col j=lane lives in s_{j&3} at lane j>>2
    const int srcl = lane >> 2;
    const float v0 = __shfl(s0, srcl);
    const float v1 = __shfl(s1, srcl);
    const float v2 = __shfl(s2, srcl);
    const float v3 = __shfl(s3, srcl);
    const int r2 = lane & 3;
    const float sg = (r2 & 2) ? ((r2 & 1) ? v3 : v2) : ((r2 & 1) ? v1 : v0);
    const float agg = sg / fmaxf((float)c, 1.0f);
    const float xv = x[(long)i * H + lane];
    float a0 = 0.f, a1 = 0.f;
#pragma unroll
    for (int k = 0; k < H; k += 2) {
      a0 += bcastf(xv, k)     * wr[k];
      a1 += bcastf(xv, k + 1) * wr[k + 1];
    }
    float acc = agg + bj + a0 + a1;
    if (relu) acc = fmaxf(acc, 0.0f);
    if (out32) out32[(long)i * H + lane] = acc;
    else       out16[(long)i * H + lane] = (_Float16)acc;
  }
}

// out[e] = sum_j relu(P[r,j] + Q[c,j] + db1[j]) * dW2[j] + db2  (P,Q fp16)
// r6: quad-edge loads — one f16x4 wave-load fetches 4 edges' P rows
// (group g = edge, sub = row slice); 2 loads per 4 edges vs 8. NL%4==0.
__global__ __launch_bounds__(256, 4) void edge_kernel(
    const int* __restrict__ row, const int* __restrict__ col,
    const _Float16* __restrict__ P, const _Float16* __restrict__ Q,
    const float* __restrict__ db1, const float* __restrict__ dW2,
    const float* __restrict__ db2, float* __restrict__ out)
{
  const int lane = threadIdx.x & 63;
  const int gw = (blockIdx.x * 256 + threadIdx.x) >> 6;
  const int nw = (gridDim.x * 256) >> 6;
  const int g = lane >> 4;
  const int sub = lane & 15;
  const f32x4 bj4 = *(const f32x4*)(db1 + 4 * sub);
  const f32x4 w24 = *(const f32x4*)(dW2 + 4 * sub);
  const float b2 = db2[0];
  for (int e = gw * 4; e < NL; e += nw * 4) {
    const int r0 = row[e], r1 = row[e + 1], r2i = row[e + 2], r3 = row[e + 3];
    const int c0 = col[e], c1 = col[e + 1], c2i = col[e + 2], c3 = col[e + 3];
    const int rs = sel4(g, r0, r1, r2i, r3);
    const int cs = sel4(g, c0, c1, c2i, c3);
    const f16x4 pv = *(const f16x4*)(P + (long)rs * H + sub * 4);
    const f16x4 qv = *(const f16x4*)(Q + (long)cs * H + sub * 4);
    float h = fmaxf((float)pv[0] + (float)qv[0] + bj4[0], 0.f) * w24[0]
            + fmaxf((float)pv[1] + (float)qv[1] + bj4[1], 0.f) * w24[1]
            + fmaxf((float)pv[2] + (float)qv[2] + bj4[2], 0.f) * w24[2]
            + fmaxf((float)pv[3] + (float)qv[3] + bj4[3], 0.f) * w24[3];
    h += __shfl_xor(h, 1);
    h += __shfl_xor(h, 2);
    h += __shfl_xor(h, 4);
    h += __shfl_xor(h, 8);
    if (sub == 0) out[e + g] = h + b2;
  }
}

extern "C" void kernel_launch(void* const* d_in, const int* in_sizes, int n_in,
                              void* d_out, int out_size, void* d_ws, size_t ws_size,
                              hipStream_t stream) {
  const float* emb_loc = (const float*)d_in[0];
  const float* emb_exp = (const float*)d_in[1];
  const float* W1l_of  = (const float*)d_in[2];
  const float* b1_of   = (const float*)d_in[3];
  const float* W1r_of  = (const float*)d_in[4];
  const float* W1l_rev = (const float*)d_in[5];
  const float* b1_rev  = (const float*)d_in[6];
  const float* W1r_rev = (const float*)d_in[7];
  const float* W2l_of  = (const float*)d_in[8];
  const float* b2_of   = (const float*)d_in[9];
  const float* W2r_of  = (const float*)d_in[10];
  const float* W2l_rev = (const float*)d_in[11];
  const float* b2_rev  = (const float*)d_in[12];
  const float* W2r_rev = (const float*)d_in[13];
  const float* dW1     = (const float*)d_in[14];
  const float* db1     = (const float*)d_in[15];
  const float* dW2     = (const float*)d_in[16];
  const float* db2     = (const float*)d_in[17];
  const int*   edge_of = (const int*)d_in[18];
  const int*   eli     = (const int*)d_in[20];

  const int* src = edge_of;
  const int* dst = edge_of + NE;
  const int* row = eli;
  const int* col = eli + NL;

  if (ws_size < WS_NEED) return;

  char* ws = (char*)d_ws;
  int*            cnt_loc = (int*)(ws);
  int*            cnt_exp = (int*)(ws + 80000);
  int*            nbr_loc = (int*)(ws + 880064);
  unsigned short* nbr_exp = (unsigned short*)(ws + 11120064);
  _Float16*       Ylh     = (_Float16*)(ws + 23920064);
  _Float16*       Y2fh    = (_Float16*)(ws + 26480064);
  float*          z_loc   = (float*)(ws + 29040064);
  _Float16*       PH      = (_Float16*)(ws + 34160064);
  _Float16*       W1rT16  = (_Float16*)(ws + 36720064);
  _Float16*       W1lrT16 = (_Float16*)(ws + 36728256);
  _Float16*       WfqT16  = (_Float16*)(ws + 36736448);
  _Float16*       Wft2T16 = (_Float16*)(ws + 36744640);
  _Float16*       ZE      = (_Float16*)(ws + 39280064);
  _Float16*       TH      = (_Float16*)(ws + 64880064);
  // fill-time aliases over the TH region (dead until mfma pass #1)
  u32*            expQ    = (u32*)(ws + 64880064);
  u32*            locQ    = (u32*)(ws + 72220096);
  int*            qcnt    = (int*)(ws + 79551936);
  int*            flbk    = (int*)(ws + 79553552);
  u64*            flbkQ   = (u64*)(ws + 79554048);
  float*          Wf_q    = (float*)(ws + 90480064);
  float*          Wf_y2   = (float*)(ws + 90496448);
  float*          Wf_t2   = (float*)(ws + 90512832);
  float*          Wf_p    = (float*)(ws + 90529216);
  float*          bf_q    = (float*)(ws + 90545600);
  float*          bf_p    = (float*)(ws + 90545856);
  float*          out     = (float*)d_out;

  // zero queue counters + fallback counter only
  (void)hipMemsetAsync(ws + 79551936, 0, 2048, stream);

  // ---- CSR fill: bin -> build (full-line writes) ----
  bin_kernel<<<NBIN, 256, 0, stream>>>(src, dst, expQ, locQ, qcnt, flbk, flbkQ);
  build_kernel<<<NBE + NBL, 256, 0, stream>>>(expQ, locQ, qcnt,
      nbr_exp, nbr_loc, cnt_exp, cnt_loc);
  // fold(+f16 transposes) + fallback drain + W transposes + dense#1
  prep_kernel<<<1258, 256, 0, stream>>>(W2r_of, W2l_of, W2l_rev, W2r_rev,
                                        dW1, b2_of, b2_rev,
                                        Wf_q, Wf_y2, Wf_t2, Wf_p, bf_q, bf_p,
                                        flbk, flbkQ, nbr_exp, nbr_loc,
                                        cnt_exp, cnt_loc,
                                        emb_loc, Ylh, W1l_of,
                                        W1r_of, W1l_rev,
                                        W1rT16, W1lrT16, WfqT16, Wft2T16);

  // ---- layer 1 ----
  // passA: z_exph = relu(emb_exp@W1r_of + gatherE(Ylh) + b1_of); T1h = emb_exp@W1l_rev
  mfma_pass_kernel<<<NEXP / 16, 256, 0, stream>>>(nbr_exp, cnt_exp, Ylh,
      emb_exp, (const _Float16*)nullptr, ZE, W1rT16, b1_of, 1, TH, W1lrT16);
  loc_gather_kernel<<<2048, 256, 0, stream>>>(nbr_loc, cnt_loc, TH,
      emb_loc, z_loc, (_Float16*)nullptr, W1r_rev, b1_rev, NLOC, 1);

  // ---- layer 2 + decoder transforms (folded: no relu on layer 2) ----
  dense_linear_kernel<<<1280, 256, 0, stream>>>(z_loc, Y2fh, Wf_y2, NLOC);
  // passB: Qh = z_exph@Wf_q + gatherE(Y2fh) + bf_q (in-place over ZE);
  //        T2'h = z_exph@Wf_t2 (over TH; T1h consumed)
  mfma_pass_kernel<<<NEXP / 16, 256, 0, stream>>>(nbr_exp, cnt_exp, Y2fh,
      (const float*)nullptr, ZE, ZE, WfqT16, bf_q, 0, TH, Wft2T16);
  // PH = gatherL(T2'h) + z_loc@Wf_p + bf_p   (decoder-left, folded, fp16 out)
  loc_gather_kernel<<<2048, 256, 0, stream>>>(nbr_loc, cnt_loc, TH,
      z_loc, (float*)nullptr, PH, Wf_p, bf_p, NLOC, 0);

  // ---- decoder edge pass ----
  edge_kernel<<<2048, 256, 0, stream>>>(row, col, PH, ZE,
                                        db1, dW2, db2, out);
}